// Round 13
// baseline (118.089 us; speedup 1.0000x reference)
//
#include <hip/hip_runtime.h>
#include <hip/hip_bf16.h>
#include <stdint.h>

typedef __attribute__((ext_vector_type(8))) short bf16x8;
typedef __attribute__((ext_vector_type(4))) short bf16x4;
typedef __attribute__((ext_vector_type(4))) float f32x4;
typedef __attribute__((ext_vector_type(16))) float f32x16;

#define B_ 2
#define H_ 16
#define S_ 2048
#define D_ 1024
#define DH 64

__device__ __forceinline__ void gload_lds16(const void* g, void* l) {
  __builtin_amdgcn_global_load_lds((const __attribute__((address_space(1))) void*)g,
                                   (__attribute__((address_space(3))) void*)l, 16, 0, 0);
}

__device__ __forceinline__ float exp2_hw(float x) {
  float r;
  asm("v_exp_f32 %0, %1" : "=v"(r) : "v"(x));
  return r;
}

__device__ __forceinline__ uint32_t packbf2(float lo, float hi) {
  union { __hip_bfloat162 h; uint32_t u; } u;
  u.h = __float22bfloat162_rn(make_float2(lo, hi));
  return u.u;
}

__device__ __forceinline__ void pl32swap(uint32_t& a, uint32_t& b) {
  asm volatile("v_permlane32_swap_b32 %0, %1" : "+v"(a), "+v"(b));
}

// ------- merged prep: fp32->bf16 converts (query,qk_w,out_w) + V transpose ----------
__global__ void k_prep(const float* __restrict__ a, __hip_bfloat16* __restrict__ da,
                       const float* __restrict__ b, __hip_bfloat16* __restrict__ db,
                       const float* __restrict__ c, __hip_bfloat16* __restrict__ dc,
                       const float* __restrict__ v, __hip_bfloat16* __restrict__ vt) {
  __shared__ float tile[64][65];
  const int bid = blockIdx.x;
  const int t = threadIdx.x;
  if (bid < 3584) {
    int i = bid * 256 + t;
    const float* src;
    __hip_bfloat16* dst;
    int off;
    if (i < 524288) { src = a; dst = da; off = i; }
    else if (i < 786432) { src = b; dst = db; off = i - 524288; }
    else { src = c; dst = dc; off = i - 786432; }
    const float4* p = (const float4*)src + (size_t)off * 2;
    float4 x = p[0], y = p[1];
    union { bf16x8 v8; __hip_bfloat16 h[8]; } u;
    u.h[0] = __float2bfloat16(x.x); u.h[1] = __float2bfloat16(x.y);
    u.h[2] = __float2bfloat16(x.z); u.h[3] = __float2bfloat16(x.w);
    u.h[4] = __float2bfloat16(y.x); u.h[5] = __float2bfloat16(y.y);
    u.h[6] = __float2bfloat16(y.z); u.h[7] = __float2bfloat16(y.w);
    *((bf16x8*)dst + off) = u.v8;
    return;
  }
  const int vid = bid - 3584;
  const int bh = vid >> 5, bb = bh >> 4, h = bh & 15;
  const int s0 = (vid & 31) * 64;
#pragma unroll
  for (int it = 0; it < 4; ++it) {
    const int r = it * 16 + (t >> 4);
    const int cc = (t & 15) * 4;
    const float4 x = *(const float4*)(v + (size_t)(bb * S_ + s0 + r) * D_ + h * DH + cc);
    tile[r][cc] = x.x; tile[r][cc + 1] = x.y; tile[r][cc + 2] = x.z; tile[r][cc + 3] = x.w;
  }
  __syncthreads();
#pragma unroll
  for (int it = 0; it < 4; ++it) {
    const int d = it * 16 + (t >> 4);
    const int j = (t & 15) * 4;
    union { bf16x4 v4; __hip_bfloat16 e[4]; } u;
    u.e[0] = __float2bfloat16(tile[j][d]);
    u.e[1] = __float2bfloat16(tile[j + 1][d]);
    u.e[2] = __float2bfloat16(tile[j + 2][d]);
    u.e[3] = __float2bfloat16(tile[j + 3][d]);
    *(bf16x4*)(vt + (size_t)(bh * DH + d) * S_ + s0 + j) = u.v4;
  }
}

// ------- 128x128 GEMM core: BK=32 dbuf with counted vmcnt (attn-proven pattern) -----
// Old core exposed full load latency each K-step (__syncthreads drains vmcnt(0)).
// Now: STAGE(next) -> vmcnt(4) (prev tile landed, new 4 stay in flight) -> s_barrier
// -> compute(cur) -> s_barrier. Same hazard structure as the proven k_attn loop.
__device__ __forceinline__ void gemm_core(
    const __hip_bfloat16* __restrict__ A, const __hip_bfloat16* __restrict__ Bm,
    int m0, int n0, __hip_bfloat16* As, __hip_bfloat16* Bs, f32x4 acc[4][4]) {
  const int t = threadIdx.x;
  const int l = t & 63, w = t >> 6;
  const int wr = w >> 1, wc = w & 1;
  const int lr = l & 15, lc = l >> 4;
  const int srow = t >> 2;
  const int sbyte = ((t & 3) << 4) ^ ((srow & 3) << 4);
  const char* AsB = (const char*)As;
  const char* BsB = (const char*)Bs;
  const int aswz = (lc << 4) ^ ((lr & 3) << 4);
  const __hip_bfloat16* gA0 = A + (size_t)(m0 + srow) * 1024 + (sbyte >> 1);
  const __hip_bfloat16* gB0 = Bm + (size_t)(n0 + srow) * 1024 + (sbyte >> 1);

#define GSTAGE(bi, k0)                                                      \
  {                                                                         \
    __hip_bfloat16* la = As + (bi) * 4096;                                  \
    __hip_bfloat16* lb = Bs + (bi) * 4096;                                  \
    gload_lds16(gA0 + (k0), la + t * 8);                                    \
    gload_lds16(gA0 + (size_t)64 * 1024 + (k0), la + (256 + t) * 8);        \
    gload_lds16(gB0 + (k0), lb + t * 8);                                    \
    gload_lds16(gB0 + (size_t)64 * 1024 + (k0), lb + (256 + t) * 8);        \
  }

  GSTAGE(0, 0)
  int buf = 0;
  for (int it = 0; it < 32; ++it) {
    if (it < 31) {
      GSTAGE(buf ^ 1, (it + 1) * 32)
      asm volatile("s_waitcnt vmcnt(4)" ::: "memory");
    } else {
      asm volatile("s_waitcnt vmcnt(0)" ::: "memory");
    }
    __builtin_amdgcn_s_barrier();
    __builtin_amdgcn_sched_barrier(0);
    const char* ab = AsB + buf * 8192;
    const char* bb = BsB + buf * 8192;
    bf16x8 af[4], bv[4];
#pragma unroll
    for (int i = 0; i < 4; ++i)
      af[i] = *(const bf16x8*)(ab + (wr * 64 + i * 16 + lr) * 64 + aswz);
#pragma unroll
    for (int j = 0; j < 4; ++j)
      bv[j] = *(const bf16x8*)(bb + (wc * 64 + j * 16 + lr) * 64 + aswz);
#pragma unroll
    for (int i = 0; i < 4; ++i)
#pragma unroll
      for (int j = 0; j < 4; ++j)
        acc[i][j] = __builtin_amdgcn_mfma_f32_16x16x32_bf16(af[i], bv[j], acc[i][j], 0, 0, 0);
    asm volatile("" ::: "memory");
    __builtin_amdgcn_s_barrier();
    buf ^= 1;
  }
#undef GSTAGE
}

// ---------------- GEMM1: qk proj, scatter into Qh/Kh [B*H, S, dh] bf16 --------------
__global__ __launch_bounds__(256) void k_gemm_qk(
    const __hip_bfloat16* __restrict__ A, const __hip_bfloat16* __restrict__ Bm,
    const float* __restrict__ bias,
    __hip_bfloat16* __restrict__ Qh, __hip_bfloat16* __restrict__ Kh) {
  __shared__ __align__(16) __hip_bfloat16 As[2][128 * 32];
  __shared__ __align__(16) __hip_bfloat16 Bs[2][128 * 32];
  f32x4 acc[4][4] = {};
  const int m0 = blockIdx.x * 128, n0 = blockIdx.y * 128;
  gemm_core(A, Bm, m0, n0, &As[0][0], &Bs[0][0], acc);
  const int t = threadIdx.x, l = t & 63, w = t >> 6;
  const int wr = w >> 1, wc = w & 1, lr = l & 15, lc = l >> 4;
#pragma unroll
  for (int j = 0; j < 4; ++j) {
    const int col = n0 + wc * 64 + j * 16 + lr;
    const float bv = bias[col];
    const int inK = col >> 10;  // 0 -> Q half, 1 -> K half
    const int hh = (col & 1023) >> 6, dd = col & 63;
    __hip_bfloat16* dst = inK ? Kh : Qh;
    // fold softmax scale D^-0.5 AND log2e into Q (attn exp runs in log2 domain)
    const float sc = inK ? 1.0f : 0.045084220f;
#pragma unroll
    for (int i = 0; i < 4; ++i) {
#pragma unroll
      for (int r = 0; r < 4; ++r) {
        const int row = m0 + wr * 64 + i * 16 + lc * 4 + r;
        const int b = row >> 11, s = row & 2047;
        const float vv = (acc[i][j][r] + bv) * sc;
        dst[((size_t)(b * H_ + hh) * S_ + s) * DH + dd] = __float2bfloat16(vv);
      }
    }
  }
}

// ---------------- GEMM2: out proj, fp32 output --------------------------------------
__global__ __launch_bounds__(256) void k_gemm_out(
    const __hip_bfloat16* __restrict__ A, const __hip_bfloat16* __restrict__ Bm,
    const float* __restrict__ bias, float* __restrict__ out) {
  __shared__ __align__(16) __hip_bfloat16 As[2][128 * 32];
  __shared__ __align__(16) __hip_bfloat16 Bs[2][128 * 32];
  f32x4 acc[4][4] = {};
  const int m0 = blockIdx.x * 128, n0 = blockIdx.y * 128;
  gemm_core(A, Bm, m0, n0, &As[0][0], &Bs[0][0], acc);
  const int t = threadIdx.x, l = t & 63, w = t >> 6;
  const int wr = w >> 1, wc = w & 1, lr = l & 15, lc = l >> 4;
#pragma unroll
  for (int j = 0; j < 4; ++j) {
    const int col = n0 + wc * 64 + j * 16 + lr;
    const float bv = bias[col];
#pragma unroll
    for (int i = 0; i < 4; ++i) {
#pragma unroll
      for (int r = 0; r < 4; ++r) {
        const int row = m0 + wr * 64 + i * 16 + lc * 4 + r;
        out[(size_t)row * D_ + col] = acc[i][j][r] + bv;
      }
    }
  }
}

// ----------- flash attention: in-block 2-way KV split, 8 waves (2 groups) -----------
// (byte-identical to the proven R12 kernel: XCD bh-remap + counted-vmcnt dbuf)
__global__ __launch_bounds__(512, 4) void k_attn(
    const __hip_bfloat16* __restrict__ Qh, const __hip_bfloat16* __restrict__ Kh,
    const __hip_bfloat16* __restrict__ VT, __hip_bfloat16* __restrict__ aO) {
  __shared__ __align__(16) __hip_bfloat16 KV[2][2][8192];  // [group][buf]: K[0:4096] V[4096:8192]
  __shared__ float lsums[2][128];
  // XCD remap: orig = y*16 + x; xcd = orig&7 -> bh = xcd*4 + (idx>>4), qtile = idx&15
  const int orig = blockIdx.x + blockIdx.y * 16;
  const int xcd = orig & 7, idx = orig >> 3;
  const int bh = xcd * 4 + (idx >> 4);
  const int q0 = (idx & 15) * 128;
  const int t = threadIdx.x;
  const int g = t >> 8;        // KV-half group
  const int tg = t & 255;      // thread-in-group
  const int l = t & 63;
  const int wg = (t >> 6) & 3; // wave-in-group
  const int qi = l & 31, hi = l >> 5;
  const int jbeg = g << 10, jend = jbeg + 1024;
  const __hip_bfloat16* Qb = Qh + (size_t)bh * S_ * DH;
  const __hip_bfloat16* Kb = Kh + (size_t)bh * S_ * DH;
  const __hip_bfloat16* Vb = VT + (size_t)bh * DH * S_;

  // hoist Q: lane holds Q[q0+wg*32+qi][dc*16 + hi*8 + 0..7] (log2e/32 pre-folded)
  bf16x8 qf[4];
#pragma unroll
  for (int dc = 0; dc < 4; ++dc)
    qf[dc] = *(const bf16x8*)&Qb[(size_t)(q0 + wg * 32 + qi) * DH + dc * 16 + hi * 8];

  const int tr = tg >> 4, tc = tg & 15;
  const int c0 = tc ^ (tr & 15);
  const int c1 = tc ^ ((tr + 16) & 15);
  const __hip_bfloat16* gK0 = Kb + (size_t)(tr + (c0 >= 8 ? 32 : 0)) * DH + (c0 & 7) * 8;
  const __hip_bfloat16* gK1 = Kb + (size_t)(tr + 16 + (c1 >= 8 ? 32 : 0)) * DH + (c1 & 7) * 8;
  const __hip_bfloat16* gV0 = Vb + (size_t)(tr + (c0 >= 8 ? 32 : 0)) * S_ + (c0 & 7) * 8;
  const __hip_bfloat16* gV1 = Vb + (size_t)(tr + 16 + (c1 >= 8 ? 32 : 0)) * S_ + (c1 & 7) * 8;

#define STAGE(bufi, j0)                                              \
  {                                                                  \
    __hip_bfloat16* Ld = &KV[g][bufi][0];                            \
    gload_lds16(gK0 + (size_t)(j0) * DH, Ld + tg * 8);               \
    gload_lds16(gK1 + (size_t)(j0) * DH, Ld + 2048 + tg * 8);        \
    gload_lds16(gV0 + (j0), Ld + 4096 + tg * 8);                     \
    gload_lds16(gV1 + (j0), Ld + 4096 + 2048 + tg * 8);              \
  }

  f32x16 oacc0 = {}, oacc1 = {};
  float lsum = 0.f;
  int buf = 0;

  STAGE(0, jbeg)

  const int rsw = (qi & 15) << 4;  // read-side XOR (row = qi for all our reads)

  for (int j0 = jbeg; j0 < jend; j0 += 64) {
    if (j0 + 64 < jend) {
      STAGE(buf ^ 1, j0 + 64)
      asm volatile("s_waitcnt vmcnt(4)" ::: "memory");
    } else {
      asm volatile("s_waitcnt vmcnt(0)" ::: "memory");
    }
    __builtin_amdgcn_s_barrier();
    __builtin_amdgcn_sched_barrier(0);
    const char* KsB = (const char*)&KV[g][buf][0];
    const char* VsB = (const char*)&KV[g][buf][4096];

    // scores: C[k][q] = sum_d K[k][d] Q[q][d]  (two 32-k subtiles)
    f32x16 s0 = {}, s1 = {};
    __builtin_amdgcn_s_setprio(1);
#pragma unroll
    for (int dc = 0; dc < 4; ++dc) {
      const int cb = dc * 32 + hi * 16;
      const bf16x8 kf0 = *(const bf16x8*)(KsB + qi * 256 + (cb ^ rsw));
      const bf16x8 kf1 = *(const bf16x8*)(KsB + qi * 256 + ((128 + cb) ^ rsw));
      s0 = __builtin_amdgcn_mfma_f32_32x32x16_bf16(kf0, qf[dc], s0, 0, 0, 0);
      s1 = __builtin_amdgcn_mfma_f32_32x32x16_bf16(kf1, qf[dc], s1, 0, 0, 0);
    }
    __builtin_amdgcn_s_setprio(0);

    // P = exp2(s) directly (no max), running row-sum via in-lane tree + one swap
#pragma unroll
    for (int r = 0; r < 16; ++r) s0[r] = exp2_hw(s0[r]);
#pragma unroll
    for (int r = 0; r < 16; ++r) s1[r] = exp2_hw(s1[r]);
    float ts[16];
#pragma unroll
    for (int r = 0; r < 16; ++r) ts[r] = s0[r] + s1[r];
#pragma unroll
    for (int st = 8; st > 0; st >>= 1)
#pragma unroll
      for (int r = 0; r < st; ++r) ts[r] += ts[r + st];
    lsum += ts[0] + __shfl_xor(ts[0], 32, 64);

    // P -> bf16 A-fragments in-register (pack + permlane32_swap), then PV
#define PVSTEP(SS, KSOFF)                                                         \
  {                                                                               \
    uint32_t w0 = packbf2(SS[0], SS[1]), w1 = packbf2(SS[2], SS[3]);              \
    uint32_t w2 = packbf2(SS[4], SS[5]), w3 = packbf2(SS[6], SS[7]);              \
    uint32_t w4 = packbf2(SS[8], SS[9]), w5 = packbf2(SS[10], SS[11]);            \
    uint32_t w6 = packbf2(SS[12], SS[13]), w7 = packbf2(SS[14], SS[15]);          \
    pl32swap(w0, w2); pl32swap(w1, w3); pl32swap(w4, w6); pl32swap(w5, w7);       \
    union { bf16x8 v; uint32_t u[4]; } pa0, pa1;                                  \
    pa0.u[0] = w0; pa0.u[1] = w1; pa0.u[2] = w2; pa0.u[3] = w3;                   \
    pa1.u[0] = w4; pa1.u[1] = w5; pa1.u[2] = w6; pa1.u[3] = w7;                   \
    const int cb = (KSOFF) + hi * 16;                                             \
    bf16x8 vf;                                                                    \
    vf = *(const bf16x8*)(VsB + qi * 256 + ((cb + 0) ^ rsw));                     \
    oacc0 = __builtin_amdgcn_mfma_f32_32x32x16_bf16(pa0.v, vf, oacc0, 0, 0, 0);   \
    vf = *(const bf16x8*)(VsB + qi * 256 + ((cb + 32) ^ rsw));                    \
    oacc0 = __builtin_amdgcn_mfma_f32_32x32x16_bf16(pa1.v, vf, oacc0, 0, 0, 0);   \
    vf = *(const bf16x8*)(VsB + qi * 256 + ((cb + 128) ^ rsw));                   \
    oacc1 = __builtin_amdgcn_mfma_f32_32x32x16_bf16(pa0.v, vf, oacc1, 0, 0, 0);   \
    vf = *(const bf16x8*)(VsB + qi * 256 + ((cb + 128 + 32) ^ rsw));              \
    oacc1 = __builtin_amdgcn_mfma_f32_32x32x16_bf16(pa1.v, vf, oacc1, 0, 0, 0);   \
  }
    __builtin_amdgcn_s_setprio(1);
    PVSTEP(s0, 0)
    PVSTEP(s1, 64)
    __builtin_amdgcn_s_setprio(0);

    asm volatile("" ::: "memory");
    __builtin_amdgcn_s_barrier();
    buf ^= 1;
  }

  // ---- in-block combine: stage unnormalized O + l in LDS (aliases dead KV) ----
  __syncthreads();  // all reads of KV done before we overwrite it
  char* OstB = (char*)&KV[0][0][0];  // group g region at g*16384 bytes
#pragma unroll
  for (int r = 0; r < 16; ++r) {
    const int qloc = (r & 3) + 8 * (r >> 2) + 4 * hi;
    const int qrow = wg * 32 + qloc;
    const int base = g * 16384 + qrow * 128;
    const int w0s = (qi >> 3) ^ (qrow & 7);
    const int w1s = (4 + (qi >> 3)) ^ (qrow & 7);
    *(__hip_bfloat16*)(OstB + base + (w0s << 4) + ((2 * qi) & 15)) =
        __float2bfloat16(oacc0[r]);
    *(__hip_bfloat16*)(OstB + base + (w1s << 4) + ((2 * qi) & 15)) =
        __float2bfloat16(oacc1[r]);
  }
  if (l < 32) lsums[g][wg * 32 + qi] = lsum;
  __syncthreads();

  // combine + normalized write: thread t handles q = t>>2, 16 d-elems (2 swz slots)
  {
    const int q = t >> 2, a = t & 3;
    const float inv = 1.0f / (lsums[0][q] + lsums[1][q]);
    const int bb = bh >> 4, h = bh & 15;
    const int off0 = q * 128 + (((2 * a) ^ (q & 7)) << 4);
    const int off1 = q * 128 + (((2 * a + 1) ^ (q & 7)) << 4);
    union { bf16x8 v; __hip_bfloat16 e[8]; } v0, v1, u0, u1;
    v0.v = *(const bf16x8*)(OstB + off0);
    v1.v = *(const bf16x8*)(OstB + 16384 + off0);
#pragma unroll
    for (int e = 0; e < 8; ++e)
      u0.e[e] = __float2bfloat16(inv * (__bfloat162float(v0.e[e]) + __bfloat162float(v1.e[e])));
    v0.v = *(const bf16x8*)(OstB + off1);
    v1.v = *(const bf16x8*)(OstB + 16384 + off1);
#pragma unroll
    for (int e = 0; e < 8; ++e)
      u1.e[e] = __float2bfloat16(inv * (__bfloat162float(v0.e[e]) + __bfloat162float(v1.e[e])));
    __hip_bfloat16* o = aO + ((size_t)(bb * S_) + q0 + q) * D_ + h * DH + a * 16;
    *(bf16x8*)o = u0.v;
    *(bf16x8*)(o + 8) = u1.v;
  }
#undef STAGE
#undef PVSTEP
}

extern "C" void kernel_launch(void* const* d_in, const int* in_sizes, int n_in,
                              void* d_out, int out_size, void* d_ws, size_t ws_size,
                              hipStream_t stream) {
  const float* q   = (const float*)d_in[0];
  // d_in[1] ("key") is unused by the reference forward.
  const float* val = (const float*)d_in[2];
  const float* qkw = (const float*)d_in[3];
  const float* qkb = (const float*)d_in[4];
  const float* ow  = (const float*)d_in[5];
  const float* ob  = (const float*)d_in[6];
  float* out = (float*)d_out;

  __hip_bfloat16* ws  = (__hip_bfloat16*)d_ws;
  __hip_bfloat16* qA  = ws;              // 4096x1024 bf16 (dead after GEMM1)
  __hip_bfloat16* w1b = qA + 4194304;    // 2048x1024 (dead after GEMM1)
  __hip_bfloat16* w2b = w1b + 2097152;   // 1024x1024 (live until gemm_out)
  __hip_bfloat16* Qh  = w2b + 1048576;   // [32][2048][64]
  __hip_bfloat16* Kh  = Qh + 4194304;    // [32][2048][64]
  __hip_bfloat16* VT  = Kh + 4194304;    // [32][64][2048]
  __hip_bfloat16* aO  = VT + 4194304;    // [B,S,D] (written by attn)

  hipLaunchKernelGGL(k_prep, dim3(4608), dim3(256), 0, stream, q, qA, qkw, w1b, ow, w2b, val, VT);
  hipLaunchKernelGGL(k_gemm_qk, dim3(32, 16), dim3(256), 0, stream, qA, w1b, qkb, Qh, Kh);
  hipLaunchKernelGGL(k_attn, dim3(16, 32), dim3(512), 0, stream, Qh, Kh, VT, aO);
  hipLaunchKernelGGL(k_gemm_out, dim3(32, 8), dim3(256), 0, stream, aO, w2b, ob, out);
}

// Round 14
// 110.551 us; speedup vs baseline: 1.0682x; 1.0682x over previous
//
#include <hip/hip_runtime.h>
#include <hip/hip_bf16.h>
#include <stdint.h>

typedef __attribute__((ext_vector_type(8))) short bf16x8;
typedef __attribute__((ext_vector_type(4))) short bf16x4;
typedef __attribute__((ext_vector_type(4))) float f32x4;
typedef __attribute__((ext_vector_type(16))) float f32x16;

#define B_ 2
#define H_ 16
#define S_ 2048
#define D_ 1024
#define DH 64

__device__ __forceinline__ void gload_lds16(const void* g, void* l) {
  __builtin_amdgcn_global_load_lds((const __attribute__((address_space(1))) void*)g,
                                   (__attribute__((address_space(3))) void*)l, 16, 0, 0);
}

__device__ __forceinline__ float exp2_hw(float x) {
  float r;
  asm("v_exp_f32 %0, %1" : "=v"(r) : "v"(x));
  return r;
}

__device__ __forceinline__ uint32_t packbf2(float lo, float hi) {
  union { __hip_bfloat162 h; uint32_t u; } u;
  u.h = __float22bfloat162_rn(make_float2(lo, hi));
  return u.u;
}

__device__ __forceinline__ void pl32swap(uint32_t& a, uint32_t& b) {
  asm volatile("v_permlane32_swap_b32 %0, %1" : "+v"(a), "+v"(b));
}

// ------- merged prep: fp32->bf16 converts (query,qk_w,out_w) + V transpose ----------
__global__ void k_prep(const float* __restrict__ a, __hip_bfloat16* __restrict__ da,
                       const float* __restrict__ b, __hip_bfloat16* __restrict__ db,
                       const float* __restrict__ c, __hip_bfloat16* __restrict__ dc,
                       const float* __restrict__ v, __hip_bfloat16* __restrict__ vt) {
  __shared__ float tile[64][65];
  const int bid = blockIdx.x;
  const int t = threadIdx.x;
  if (bid < 3584) {
    int i = bid * 256 + t;
    const float* src;
    __hip_bfloat16* dst;
    int off;
    if (i < 524288) { src = a; dst = da; off = i; }
    else if (i < 786432) { src = b; dst = db; off = i - 524288; }
    else { src = c; dst = dc; off = i - 786432; }
    const float4* p = (const float4*)src + (size_t)off * 2;
    float4 x = p[0], y = p[1];
    union { bf16x8 v8; __hip_bfloat16 h[8]; } u;
    u.h[0] = __float2bfloat16(x.x); u.h[1] = __float2bfloat16(x.y);
    u.h[2] = __float2bfloat16(x.z); u.h[3] = __float2bfloat16(x.w);
    u.h[4] = __float2bfloat16(y.x); u.h[5] = __float2bfloat16(y.y);
    u.h[6] = __float2bfloat16(y.z); u.h[7] = __float2bfloat16(y.w);
    *((bf16x8*)dst + off) = u.v8;
    return;
  }
  const int vid = bid - 3584;
  const int bh = vid >> 5, bb = bh >> 4, h = bh & 15;
  const int s0 = (vid & 31) * 64;
#pragma unroll
  for (int it = 0; it < 4; ++it) {
    const int r = it * 16 + (t >> 4);
    const int cc = (t & 15) * 4;
    const float4 x = *(const float4*)(v + (size_t)(bb * S_ + s0 + r) * D_ + h * DH + cc);
    tile[r][cc] = x.x; tile[r][cc + 1] = x.y; tile[r][cc + 2] = x.z; tile[r][cc + 3] = x.w;
  }
  __syncthreads();
#pragma unroll
  for (int it = 0; it < 4; ++it) {
    const int d = it * 16 + (t >> 4);
    const int j = (t & 15) * 4;
    union { bf16x4 v4; __hip_bfloat16 e[4]; } u;
    u.e[0] = __float2bfloat16(tile[j][d]);
    u.e[1] = __float2bfloat16(tile[j + 1][d]);
    u.e[2] = __float2bfloat16(tile[j + 2][d]);
    u.e[3] = __float2bfloat16(tile[j + 3][d]);
    *(bf16x4*)(vt + (size_t)(bh * DH + d) * S_ + s0 + j) = u.v4;
  }
}

// ------- 128x128 GEMM core (R3-proven): BK=32, 2 barriers/step, no dbuf -------------
// Verdict after R4/R6/R13: at 2 blocks/CU the stage-drain is hidden by cross-block
// TLP; every explicit pipelining variant measured slower. Do not restructure.
__device__ __forceinline__ void gemm_core(
    const __hip_bfloat16* __restrict__ A, const __hip_bfloat16* __restrict__ Bm,
    int m0, int n0, __hip_bfloat16* As, __hip_bfloat16* Bs, f32x4 acc[4][4]) {
  const int t = threadIdx.x;
  const int l = t & 63, w = t >> 6;
  const int wr = w >> 1, wc = w & 1;
  const int lr = l & 15, lc = l >> 4;
  const int srow = t >> 2;
  const int sbyte = ((t & 3) << 4) ^ ((srow & 3) << 4);
  const char* AsB = (const char*)As;
  const char* BsB = (const char*)Bs;
  const int aswz = (lc << 4) ^ ((lr & 3) << 4);
  const __hip_bfloat16* gA0 = A + (size_t)(m0 + srow) * 1024 + (sbyte >> 1);
  const __hip_bfloat16* gB0 = Bm + (size_t)(n0 + srow) * 1024 + (sbyte >> 1);
  for (int k0 = 0; k0 < 1024; k0 += 32) {
    __syncthreads();
    gload_lds16(gA0 + k0, (void*)&As[t * 8]);
    gload_lds16(gA0 + (size_t)64 * 1024 + k0, (void*)&As[(256 + t) * 8]);
    gload_lds16(gB0 + k0, (void*)&Bs[t * 8]);
    gload_lds16(gB0 + (size_t)64 * 1024 + k0, (void*)&Bs[(256 + t) * 8]);
    __syncthreads();
    bf16x8 af[4], bv[4];
#pragma unroll
    for (int i = 0; i < 4; ++i)
      af[i] = *(const bf16x8*)(AsB + (wr * 64 + i * 16 + lr) * 64 + aswz);
#pragma unroll
    for (int j = 0; j < 4; ++j)
      bv[j] = *(const bf16x8*)(BsB + (wc * 64 + j * 16 + lr) * 64 + aswz);
#pragma unroll
    for (int i = 0; i < 4; ++i)
#pragma unroll
      for (int j = 0; j < 4; ++j)
        acc[i][j] = __builtin_amdgcn_mfma_f32_16x16x32_bf16(af[i], bv[j], acc[i][j], 0, 0, 0);
  }
}

// ---------------- GEMM1: qk proj, scatter into Qh/Kh [B*H, S, dh] bf16 --------------
__global__ __launch_bounds__(256) void k_gemm_qk(
    const __hip_bfloat16* __restrict__ A, const __hip_bfloat16* __restrict__ Bm,
    const float* __restrict__ bias,
    __hip_bfloat16* __restrict__ Qh, __hip_bfloat16* __restrict__ Kh) {
  __shared__ __align__(16) __hip_bfloat16 As[128 * 32];
  __shared__ __align__(16) __hip_bfloat16 Bs[128 * 32];
  f32x4 acc[4][4] = {};
  const int m0 = blockIdx.x * 128, n0 = blockIdx.y * 128;
  gemm_core(A, Bm, m0, n0, As, Bs, acc);
  const int t = threadIdx.x, l = t & 63, w = t >> 6;
  const int wr = w >> 1, wc = w & 1, lr = l & 15, lc = l >> 4;
#pragma unroll
  for (int j = 0; j < 4; ++j) {
    const int col = n0 + wc * 64 + j * 16 + lr;
    const float bv = bias[col];
    const int inK = col >> 10;  // 0 -> Q half, 1 -> K half
    const int hh = (col & 1023) >> 6, dd = col & 63;
    __hip_bfloat16* dst = inK ? Kh : Qh;
    // fold softmax scale D^-0.5 AND log2e into Q (attn exp runs in log2 domain)
    const float sc = inK ? 1.0f : 0.045084220f;
#pragma unroll
    for (int i = 0; i < 4; ++i) {
#pragma unroll
      for (int r = 0; r < 4; ++r) {
        const int row = m0 + wr * 64 + i * 16 + lc * 4 + r;
        const int b = row >> 11, s = row & 2047;
        const float vv = (acc[i][j][r] + bv) * sc;
        dst[((size_t)(b * H_ + hh) * S_ + s) * DH + dd] = __float2bfloat16(vv);
      }
    }
  }
}

// ---------------- GEMM2: out proj, fp32 output --------------------------------------
__global__ __launch_bounds__(256) void k_gemm_out(
    const __hip_bfloat16* __restrict__ A, const __hip_bfloat16* __restrict__ Bm,
    const float* __restrict__ bias, float* __restrict__ out) {
  __shared__ __align__(16) __hip_bfloat16 As[128 * 32];
  __shared__ __align__(16) __hip_bfloat16 Bs[128 * 32];
  f32x4 acc[4][4] = {};
  const int m0 = blockIdx.x * 128, n0 = blockIdx.y * 128;
  gemm_core(A, Bm, m0, n0, As, Bs, acc);
  const int t = threadIdx.x, l = t & 63, w = t >> 6;
  const int wr = w >> 1, wc = w & 1, lr = l & 15, lc = l >> 4;
#pragma unroll
  for (int j = 0; j < 4; ++j) {
    const int col = n0 + wc * 64 + j * 16 + lr;
    const float bv = bias[col];
#pragma unroll
    for (int i = 0; i < 4; ++i) {
#pragma unroll
      for (int r = 0; r < 4; ++r) {
        const int row = m0 + wr * 64 + i * 16 + lc * 4 + r;
        out[(size_t)row * D_ + col] = acc[i][j][r] + bv;
      }
    }
  }
}

// ----------- flash attention: in-block 2-way KV split, 8 waves (2 groups) -----------
// XCD bh-remap (FETCH 69.7->12.3MB) + KV tile 64 dbuf + counted vmcnt + in-LDS combine.
__global__ __launch_bounds__(512, 4) void k_attn(
    const __hip_bfloat16* __restrict__ Qh, const __hip_bfloat16* __restrict__ Kh,
    const __hip_bfloat16* __restrict__ VT, __hip_bfloat16* __restrict__ aO) {
  __shared__ __align__(16) __hip_bfloat16 KV[2][2][8192];  // [group][buf]: K[0:4096] V[4096:8192]
  __shared__ float lsums[2][128];
  // XCD remap: orig = y*16 + x; xcd = orig&7 -> bh = xcd*4 + (idx>>4), qtile = idx&15
  const int orig = blockIdx.x + blockIdx.y * 16;
  const int xcd = orig & 7, idx = orig >> 3;
  const int bh = xcd * 4 + (idx >> 4);
  const int q0 = (idx & 15) * 128;
  const int t = threadIdx.x;
  const int g = t >> 8;        // KV-half group
  const int tg = t & 255;      // thread-in-group
  const int l = t & 63;
  const int wg = (t >> 6) & 3; // wave-in-group
  const int qi = l & 31, hi = l >> 5;
  const int jbeg = g << 10, jend = jbeg + 1024;
  const __hip_bfloat16* Qb = Qh + (size_t)bh * S_ * DH;
  const __hip_bfloat16* Kb = Kh + (size_t)bh * S_ * DH;
  const __hip_bfloat16* Vb = VT + (size_t)bh * DH * S_;

  // hoist Q: lane holds Q[q0+wg*32+qi][dc*16 + hi*8 + 0..7] (log2e/32 pre-folded)
  bf16x8 qf[4];
#pragma unroll
  for (int dc = 0; dc < 4; ++dc)
    qf[dc] = *(const bf16x8*)&Qb[(size_t)(q0 + wg * 32 + qi) * DH + dc * 16 + hi * 8];

  const int tr = tg >> 4, tc = tg & 15;
  const int c0 = tc ^ (tr & 15);
  const int c1 = tc ^ ((tr + 16) & 15);
  const __hip_bfloat16* gK0 = Kb + (size_t)(tr + (c0 >= 8 ? 32 : 0)) * DH + (c0 & 7) * 8;
  const __hip_bfloat16* gK1 = Kb + (size_t)(tr + 16 + (c1 >= 8 ? 32 : 0)) * DH + (c1 & 7) * 8;
  const __hip_bfloat16* gV0 = Vb + (size_t)(tr + (c0 >= 8 ? 32 : 0)) * S_ + (c0 & 7) * 8;
  const __hip_bfloat16* gV1 = Vb + (size_t)(tr + 16 + (c1 >= 8 ? 32 : 0)) * S_ + (c1 & 7) * 8;

#define STAGE(bufi, j0)                                              \
  {                                                                  \
    __hip_bfloat16* Ld = &KV[g][bufi][0];                            \
    gload_lds16(gK0 + (size_t)(j0) * DH, Ld + tg * 8);               \
    gload_lds16(gK1 + (size_t)(j0) * DH, Ld + 2048 + tg * 8);        \
    gload_lds16(gV0 + (j0), Ld + 4096 + tg * 8);                     \
    gload_lds16(gV1 + (j0), Ld + 4096 + 2048 + tg * 8);              \
  }

  f32x16 oacc0 = {}, oacc1 = {};
  float lsum = 0.f;
  int buf = 0;

  STAGE(0, jbeg)

  const int rsw = (qi & 15) << 4;  // read-side XOR (row = qi for all our reads)

  for (int j0 = jbeg; j0 < jend; j0 += 64) {
    if (j0 + 64 < jend) {
      STAGE(buf ^ 1, j0 + 64)
      asm volatile("s_waitcnt vmcnt(4)" ::: "memory");
    } else {
      asm volatile("s_waitcnt vmcnt(0)" ::: "memory");
    }
    __builtin_amdgcn_s_barrier();
    __builtin_amdgcn_sched_barrier(0);
    const char* KsB = (const char*)&KV[g][buf][0];
    const char* VsB = (const char*)&KV[g][buf][4096];

    // scores: C[k][q] = sum_d K[k][d] Q[q][d]  (two 32-k subtiles)
    f32x16 s0 = {}, s1 = {};
    __builtin_amdgcn_s_setprio(1);
#pragma unroll
    for (int dc = 0; dc < 4; ++dc) {
      const int cb = dc * 32 + hi * 16;
      const bf16x8 kf0 = *(const bf16x8*)(KsB + qi * 256 + (cb ^ rsw));
      const bf16x8 kf1 = *(const bf16x8*)(KsB + qi * 256 + ((128 + cb) ^ rsw));
      s0 = __builtin_amdgcn_mfma_f32_32x32x16_bf16(kf0, qf[dc], s0, 0, 0, 0);
      s1 = __builtin_amdgcn_mfma_f32_32x32x16_bf16(kf1, qf[dc], s1, 0, 0, 0);
    }
    __builtin_amdgcn_s_setprio(0);

    // P = exp2(s) directly (no max), running row-sum via in-lane tree + one swap
#pragma unroll
    for (int r = 0; r < 16; ++r) s0[r] = exp2_hw(s0[r]);
#pragma unroll
    for (int r = 0; r < 16; ++r) s1[r] = exp2_hw(s1[r]);
    float ts[16];
#pragma unroll
    for (int r = 0; r < 16; ++r) ts[r] = s0[r] + s1[r];
#pragma unroll
    for (int st = 8; st > 0; st >>= 1)
#pragma unroll
      for (int r = 0; r < st; ++r) ts[r] += ts[r + st];
    lsum += ts[0] + __shfl_xor(ts[0], 32, 64);

    // P -> bf16 A-fragments in-register (pack + permlane32_swap), then PV
#define PVSTEP(SS, KSOFF)                                                         \
  {                                                                               \
    uint32_t w0 = packbf2(SS[0], SS[1]), w1 = packbf2(SS[2], SS[3]);              \
    uint32_t w2 = packbf2(SS[4], SS[5]), w3 = packbf2(SS[6], SS[7]);              \
    uint32_t w4 = packbf2(SS[8], SS[9]), w5 = packbf2(SS[10], SS[11]);            \
    uint32_t w6 = packbf2(SS[12], SS[13]), w7 = packbf2(SS[14], SS[15]);          \
    pl32swap(w0, w2); pl32swap(w1, w3); pl32swap(w4, w6); pl32swap(w5, w7);       \
    union { bf16x8 v; uint32_t u[4]; } pa0, pa1;                                  \
    pa0.u[0] = w0; pa0.u[1] = w1; pa0.u[2] = w2; pa0.u[3] = w3;                   \
    pa1.u[0] = w4; pa1.u[1] = w5; pa1.u[2] = w6; pa1.u[3] = w7;                   \
    const int cb = (KSOFF) + hi * 16;                                             \
    bf16x8 vf;                                                                    \
    vf = *(const bf16x8*)(VsB + qi * 256 + ((cb + 0) ^ rsw));                     \
    oacc0 = __builtin_amdgcn_mfma_f32_32x32x16_bf16(pa0.v, vf, oacc0, 0, 0, 0);   \
    vf = *(const bf16x8*)(VsB + qi * 256 + ((cb + 32) ^ rsw));                    \
    oacc0 = __builtin_amdgcn_mfma_f32_32x32x16_bf16(pa1.v, vf, oacc0, 0, 0, 0);   \
    vf = *(const bf16x8*)(VsB + qi * 256 + ((cb + 128) ^ rsw));                   \
    oacc1 = __builtin_amdgcn_mfma_f32_32x32x16_bf16(pa0.v, vf, oacc1, 0, 0, 0);   \
    vf = *(const bf16x8*)(VsB + qi * 256 + ((cb + 128 + 32) ^ rsw));              \
    oacc1 = __builtin_amdgcn_mfma_f32_32x32x16_bf16(pa1.v, vf, oacc1, 0, 0, 0);   \
  }
    __builtin_amdgcn_s_setprio(1);
    PVSTEP(s0, 0)
    PVSTEP(s1, 64)
    __builtin_amdgcn_s_setprio(0);

    asm volatile("" ::: "memory");
    __builtin_amdgcn_s_barrier();
    buf ^= 1;
  }

  // ---- in-block combine: stage unnormalized O + l in LDS (aliases dead KV) ----
  __syncthreads();  // all reads of KV done before we overwrite it
  char* OstB = (char*)&KV[0][0][0];  // group g region at g*16384 bytes
#pragma unroll
  for (int r = 0; r < 16; ++r) {
    const int qloc = (r & 3) + 8 * (r >> 2) + 4 * hi;
    const int qrow = wg * 32 + qloc;
    const int base = g * 16384 + qrow * 128;
    const int w0s = (qi >> 3) ^ (qrow & 7);
    const int w1s = (4 + (qi >> 3)) ^ (qrow & 7);
    *(__hip_bfloat16*)(OstB + base + (w0s << 4) + ((2 * qi) & 15)) =
        __float2bfloat16(oacc0[r]);
    *(__hip_bfloat16*)(OstB + base + (w1s << 4) + ((2 * qi) & 15)) =
        __float2bfloat16(oacc1[r]);
  }
  if (l < 32) lsums[g][wg * 32 + qi] = lsum;
  __syncthreads();

  // combine + normalized write: thread t handles q = t>>2, 16 d-elems (2 swz slots)
  {
    const int q = t >> 2, a = t & 3;
    const float inv = 1.0f / (lsums[0][q] + lsums[1][q]);
    const int bb = bh >> 4, h = bh & 15;
    const int off0 = q * 128 + (((2 * a) ^ (q & 7)) << 4);
    const int off1 = q * 128 + (((2 * a + 1) ^ (q & 7)) << 4);
    union { bf16x8 v; __hip_bfloat16 e[8]; } v0, v1, u0, u1;
    v0.v = *(const bf16x8*)(OstB + off0);
    v1.v = *(const bf16x8*)(OstB + 16384 + off0);
#pragma unroll
    for (int e = 0; e < 8; ++e)
      u0.e[e] = __float2bfloat16(inv * (__bfloat162float(v0.e[e]) + __bfloat162float(v1.e[e])));
    v0.v = *(const bf16x8*)(OstB + off1);
    v1.v = *(const bf16x8*)(OstB + 16384 + off1);
#pragma unroll
    for (int e = 0; e < 8; ++e)
      u1.e[e] = __float2bfloat16(inv * (__bfloat162float(v0.e[e]) + __bfloat162float(v1.e[e])));
    __hip_bfloat16* o = aO + ((size_t)(bb * S_) + q0 + q) * D_ + h * DH + a * 16;
    *(bf16x8*)o = u0.v;
    *(bf16x8*)(o + 8) = u1.v;
  }
#undef STAGE
#undef PVSTEP
}

extern "C" void kernel_launch(void* const* d_in, const int* in_sizes, int n_in,
                              void* d_out, int out_size, void* d_ws, size_t ws_size,
                              hipStream_t stream) {
  const float* q   = (const float*)d_in[0];
  // d_in[1] ("key") is unused by the reference forward.
  const float* val = (const float*)d_in[2];
  const float* qkw = (const float*)d_in[3];
  const float* qkb = (const float*)d_in[4];
  const float* ow  = (const float*)d_in[5];
  const float* ob  = (const float*)d_in[6];
  float* out = (float*)d_out;

  __hip_bfloat16* ws  = (__hip_bfloat16*)d_ws;
  __hip_bfloat16* qA  = ws;              // 4096x1024 bf16 (dead after GEMM1)
  __hip_bfloat16* w1b = qA + 4194304;    // 2048x1024 (dead after GEMM1)
  __hip_bfloat16* w2b = w1b + 2097152;   // 1024x1024 (live until gemm_out)
  __hip_bfloat16* Qh  = w2b + 1048576;   // [32][2048][64]
  __hip_bfloat16* Kh  = Qh + 4194304;    // [32][2048][64]
  __hip_bfloat16* VT  = Kh + 4194304;    // [32][64][2048]
  __hip_bfloat16* aO  = VT + 4194304;    // [B,S,D] (written by attn)

  hipLaunchKernelGGL(k_prep, dim3(4608), dim3(256), 0, stream, q, qA, qkw, w1b, ow, w2b, val, VT);
  hipLaunchKernelGGL(k_gemm_qk, dim3(32, 16), dim3(256), 0, stream, qA, w1b, qkb, Qh, Kh);
  hipLaunchKernelGGL(k_attn, dim3(16, 32), dim3(512), 0, stream, Qh, Kh, VT, aO);
  hipLaunchKernelGGL(k_gemm_out, dim3(32, 8), dim3(256), 0, stream, aO, w2b, ob, out);
}